// Round 2
// baseline (512.564 us; speedup 1.0000x reference)
//
#include <hip/hip_runtime.h>
#include <math.h>

#define MEXP 8
#define BTOK 4096
#define DIN  1024
#define DHID 4096
#define DOUT 1024
#define BK   32

typedef __bf16 bf16x4 __attribute__((ext_vector_type(4)));
typedef __bf16 bf16x8 __attribute__((ext_vector_type(8)));
typedef float  f32x4  __attribute__((ext_vector_type(4)));

// async global->LDS, 16B per lane. LDS dest must be wave-uniform base + lane*16.
__device__ __forceinline__ void gld16(const void* g, void* l) {
    __builtin_amdgcn_global_load_lds(
        (const __attribute__((address_space(1))) unsigned int*)g,
        (__attribute__((address_space(3))) unsigned int*)l, 16, 0, 0);
}

__device__ __forceinline__ float gelu_tanh(float v) {
    // 0.5*v*(1+tanh(u)) == v * sigmoid(2u), 2u = sqrt(8/pi)*(v + 0.044715 v^3)
    float t = 1.5957691216057308f * v * (1.0f + 0.044715f * v * v);
    return v / (1.0f + __expf(-t));
}

// ---------------- routing ----------------
__global__ void route_kernel(const int* __restrict__ route, int* __restrict__ perm,
                             int* __restrict__ offsets) {
    __shared__ int cnt[MEXP];
    __shared__ int off[MEXP + 1];
    int t = threadIdx.x;
    if (t < MEXP) cnt[t] = 0;
    __syncthreads();
    for (int i = t; i < BTOK; i += blockDim.x) atomicAdd(&cnt[route[i]], 1);
    __syncthreads();
    if (t == 0) {
        int s = 0;
        for (int m = 0; m < MEXP; m++) { off[m] = s; s += cnt[m]; }
        off[MEXP] = s;
    }
    __syncthreads();
    if (t < MEXP + 1) offsets[t] = off[t];
    if (t < MEXP) cnt[t] = off[t];
    __syncthreads();
    for (int i = t; i < BTOK; i += blockDim.x) {
        int p = atomicAdd(&cnt[route[i]], 1);
        perm[p] = i;
    }
}

// ---------------- x fp32 -> bf16 ----------------
__global__ __launch_bounds__(256) void convert_x_kernel(const float* __restrict__ x,
                                                        __bf16* __restrict__ xb) {
    int i = blockIdx.x * 256 + threadIdx.x;
    float4 v = *(const float4*)(x + (size_t)i * 4);
    bf16x4 p;
    p[0] = (__bf16)v.x; p[1] = (__bf16)v.y; p[2] = (__bf16)v.z; p[3] = (__bf16)v.w;
    *(bf16x4*)(xb + (size_t)i * 4) = p;
}

// ---------------- W [m][K][N] fp32 -> Wt [m][N][K] bf16 ----------------
template <int K, int N>
__global__ __launch_bounds__(256) void transpose_kernel(const float* __restrict__ W,
                                                        __bf16* __restrict__ Wt) {
    __shared__ float T[64][132];
    int m = blockIdx.z;
    int k0 = blockIdx.y * 64;
    int n0 = blockIdx.x * 128;
    const float* Wm = W + (size_t)m * K * N;
    __bf16* Wtm = Wt + (size_t)m * N * K;
    int t = threadIdx.x;
    int nc4 = (t & 31) * 4;
    int kr0 = t >> 5;
#pragma unroll
    for (int it = 0; it < 8; it++) {
        int kr = it * 8 + kr0;
        float4 v = *(const float4*)(Wm + (size_t)(k0 + kr) * N + n0 + nc4);
        *(float4*)&T[kr][nc4] = v;
    }
    __syncthreads();
#pragma unroll
    for (int it = 0; it < 4; it++) {
        int task = it * 256 + t;
        int nr = task >> 3;
        int gr = task & 7;
        bf16x8 v;
#pragma unroll
        for (int j = 0; j < 8; j++) {
            int j2 = (j + gr) & 7;
            v[j2] = (__bf16)T[gr * 8 + j2][nr];
        }
        *(bf16x8*)(Wtm + (size_t)(n0 + nr) * K + k0 + gr * 8) = v;
    }
}

// fragment reads + 16 MFMA on one 128x128 tile slice
#define GEMM_STAGE(Ap, Bp)                                                              \
    do {                                                                                \
        bf16x8 af[4], bfr[4];                                                           \
        _Pragma("unroll") for (int i = 0; i < 4; i++)                                   \
            af[i] = *(bf16x8*)&(Ap)[(wr + i * 16 + lm) * BK + quad * 8];                \
        _Pragma("unroll") for (int j = 0; j < 4; j++)                                   \
            bfr[j] = *(bf16x8*)&(Bp)[(wc + j * 16 + lm) * BK + quad * 8];               \
        _Pragma("unroll") for (int i = 0; i < 4; i++)                                   \
            _Pragma("unroll") for (int j = 0; j < 4; j++)                               \
                acc[i][j] = __builtin_amdgcn_mfma_f32_16x16x32_bf16(af[i], bfr[j],      \
                                                                   acc[i][j], 0, 0, 0);\
    } while (0)

#define PREFETCH(buf, kk)                                                               \
    do {                                                                                \
        gld16(gA[0] + (kk), lA[0] + (buf) * 8192);                                      \
        gld16(gA[1] + (kk), lA[1] + (buf) * 8192);                                      \
        gld16(gB[0] + (kk), lB[0] + (buf) * 8192);                                      \
        gld16(gB[1] + (kk), lB[1] + (buf) * 8192);                                      \
    } while (0)

// ---------------- GEMM1: H[perm-space] = gelu(Xb[perm] @ W1t^T + b1) ----------------
// TM=128, TN=128, BK=32, double-buffered prefetch-1. grid (DHID/128=32, 8, MEXP).
// XCD-chunked swizzle: one expert per XCD (L2-resident xb slice + B-panel reuse).
__global__ __launch_bounds__(256)
void gemm1_kernel(const __bf16* __restrict__ xb, const __bf16* __restrict__ W1t,
                  const float* __restrict__ b1, const int* __restrict__ perm,
                  const int* __restrict__ offsets, __bf16* __restrict__ H) {
    int flat = blockIdx.x + 32 * (blockIdx.y + 8 * blockIdx.z);   // [0,2048)
    int logical = (flat & 7) * 256 + (flat >> 3);                 // bijective
    int m  = logical >> 8;          // expert -> XCD
    int bx = (logical >> 3) & 31;   // col tile
    int by = logical & 7;           // row tile (fastest: B-panel sharers adjacent)

    int seg_start = offsets[m];
    int cnt = offsets[m + 1] - seg_start;
    int row0 = by * 128;
    if (row0 >= cnt) return;
    int col0 = bx * 128;

    __shared__ char smem[32768];
    __bf16* As = (__bf16*)smem;            // [2][128*BK]
    __bf16* Bs = (__bf16*)(smem + 16384);  // [2][128*BK]

    int tid = threadIdx.x;
    int wave = tid >> 6, lane = tid & 63;
    int wr = (wave >> 1) * 64, wc = (wave & 1) * 64;
    int lm = lane & 15, quad = lane >> 4;

    const __bf16* gA[2];
    char* lA[2];
    const __bf16* gB[2];
    char* lB[2];
    const __bf16* Wm = W1t + (size_t)m * DHID * DIN;
#pragma unroll
    for (int c = 0; c < 2; c++) {
        int rA = row0 + wave * 32 + c * 16 + (lane >> 2);
        int tok = perm[seg_start + (rA < cnt ? rA : cnt - 1)];
        gA[c] = xb + (size_t)tok * DIN + (lane & 3) * 8;
        lA[c] = smem + (wave * 32 + c * 16) * 64 + lane * 16;
        int nB = col0 + wave * 32 + c * 16 + (lane >> 2);
        gB[c] = Wm + (size_t)nB * DIN + (lane & 3) * 8;
        lB[c] = smem + 16384 + (wave * 32 + c * 16) * 64 + lane * 16;
    }

    f32x4 acc[4][4];
#pragma unroll
    for (int i = 0; i < 4; i++)
#pragma unroll
        for (int j = 0; j < 4; j++)
#pragma unroll
            for (int r = 0; r < 4; r++) acc[i][j][r] = 0.0f;

    const int NIT = DIN / BK;   // 32
    PREFETCH(0, 0);
    for (int it = 0; it < NIT; it += 2) {
        __syncthreads();
        if (it + 1 < NIT) PREFETCH(1, (it + 1) * BK);
        GEMM_STAGE(As, Bs);
        __syncthreads();
        if (it + 2 < NIT) PREFETCH(0, (it + 2) * BK);
        GEMM_STAGE(As + 4096, Bs + 4096);
    }

    // ---- epilogue: bias+gelu -> LDS (swizzled) -> coalesced 16B row stores ----
    __syncthreads();                       // all staging reads done before overlay
    __bf16* Ct = (__bf16*)smem;            // [128][128] bf16 = 32KB
#pragma unroll
    for (int j = 0; j < 4; j++) {
        int col = wc + j * 16 + lm;
        float bias = b1[m * DHID + col0 + col];
#pragma unroll
        for (int i = 0; i < 4; i++) {
#pragma unroll
            for (int r = 0; r < 4; r++) {
                int row = wr + i * 16 + quad * 4 + r;
                float v = acc[i][j][r] + bias;
                Ct[row * 128 + (col ^ ((row & 7) << 3))] = (__bf16)gelu_tanh(v);
            }
        }
    }
    __syncthreads();
#pragma unroll
    for (int it = 0; it < 8; it++) {
        int idx = it * 256 + tid;          // 2048 chunks of 16B
        int row = idx >> 4;
        int c = idx & 15;
        int grow = row0 + row;
        if (grow < cnt) {
            bf16x8 v = *(bf16x8*)&Ct[row * 128 + ((c * 8) ^ ((row & 7) << 3))];
            *(bf16x8*)(H + (size_t)(seg_start + grow) * DHID + col0 + c * 8) = v;
        }
    }
}

// ---------------- GEMM2 split-K=4 partial ----------------
// TM=128, TN=128, BK=32. grid (DOUT/128=8, 8, MEXP*4). XCD swizzle: expert -> XCD.
__global__ __launch_bounds__(256)
void gemm2p_kernel(const __bf16* __restrict__ H, const __bf16* __restrict__ W2t,
                   const int* __restrict__ offsets, float* __restrict__ partial) {
    int flat = blockIdx.x + 8 * (blockIdx.y + 8 * blockIdx.z);    // [0,2048)
    int logical = (flat & 7) * 256 + (flat >> 3);
    int m  = logical >> 8;          // expert -> XCD
    int s  = (logical >> 6) & 3;    // K split (slow: H slice stays in L2)
    int bx = (logical >> 3) & 7;
    int by = logical & 7;

    int seg_start = offsets[m];
    int cnt = offsets[m + 1] - seg_start;
    int row0 = by * 128;
    if (row0 >= cnt) return;
    int col0 = bx * 128;
    int kbase = s * (DHID / 4);

    __shared__ __bf16 As[2][128 * BK];
    __shared__ __bf16 Bs[2][128 * BK];

    int tid = threadIdx.x;
    int wave = tid >> 6, lane = tid & 63;
    int wr = (wave >> 1) * 64, wc = (wave & 1) * 64;
    int lm = lane & 15, quad = lane >> 4;

    const __bf16* gA[2];
    char* lA[2];
    const __bf16* gB[2];
    char* lB[2];
    const __bf16* Wm = W2t + (size_t)m * DOUT * DHID;
#pragma unroll
    for (int c = 0; c < 2; c++) {
        int rA = row0 + wave * 32 + c * 16 + (lane >> 2);
        int hr = seg_start + (rA < cnt ? rA : cnt - 1);
        gA[c] = H + (size_t)hr * DHID + kbase + (lane & 3) * 8;
        lA[c] = (char*)&As[0][0] + (wave * 32 + c * 16) * 64 + lane * 16;
        int nB = col0 + wave * 32 + c * 16 + (lane >> 2);
        gB[c] = Wm + (size_t)nB * DHID + kbase + (lane & 3) * 8;
        lB[c] = (char*)&Bs[0][0] + (wave * 32 + c * 16) * 64 + lane * 16;
    }

    f32x4 acc[4][4];
#pragma unroll
    for (int i = 0; i < 4; i++)
#pragma unroll
        for (int j = 0; j < 4; j++)
#pragma unroll
            for (int r = 0; r < 4; r++) acc[i][j][r] = 0.0f;

    const int NIT = (DHID / 4) / BK;   // 32
    PREFETCH(0, 0);
    for (int it = 0; it < NIT; it += 2) {
        __syncthreads();
        if (it + 1 < NIT) PREFETCH(1, (it + 1) * BK);
        GEMM_STAGE(As[0], Bs[0]);
        __syncthreads();
        if (it + 2 < NIT) PREFETCH(0, (it + 2) * BK);
        GEMM_STAGE(As[1], Bs[1]);
    }

    float* pdst = partial + (size_t)s * BTOK * DOUT;
#pragma unroll
    for (int j = 0; j < 4; j++) {
        int col = col0 + wc + j * 16 + lm;
#pragma unroll
        for (int i = 0; i < 4; i++) {
#pragma unroll
            for (int r = 0; r < 4; r++) {
                int row = row0 + wr + i * 16 + quad * 4 + r;
                if (row < cnt)
                    pdst[(size_t)(seg_start + row) * DOUT + col] = acc[i][j][r];
            }
        }
    }
}

// ---------------- reduce: out[perm[r]] = sum_s p[s][r] + b2[expert(r)] ----------------
__global__ __launch_bounds__(256)
void reduce_kernel(const float* __restrict__ partial, const int* __restrict__ perm,
                   const int* __restrict__ offsets, const float* __restrict__ b2,
                   float* __restrict__ out) {
    int r = blockIdx.x;
    int c4 = threadIdx.x * 4;
    int e = 0;
#pragma unroll
    for (int q = 0; q < MEXP - 1; q++)
        if (r >= offsets[q + 1]) e = q + 1;
    int tok = perm[r];
    float4 o = *(const float4*)(b2 + e * DOUT + c4);
#pragma unroll
    for (int s = 0; s < 4; s++) {
        float4 a = *(const float4*)(partial + (size_t)(s * BTOK + r) * DOUT + c4);
        o.x += a.x; o.y += a.y; o.z += a.z; o.w += a.w;
    }
    *(float4*)(out + (size_t)tok * DOUT + c4) = o;
}

extern "C" void kernel_launch(void* const* d_in, const int* in_sizes, int n_in,
                              void* d_out, int out_size, void* d_ws, size_t ws_size,
                              hipStream_t stream) {
    const float* x     = (const float*)d_in[0];
    const int*   route = (const int*)d_in[1];
    const float* W1    = (const float*)d_in[2];
    const float* b1    = (const float*)d_in[3];
    const float* W2    = (const float*)d_in[4];
    const float* b2    = (const float*)d_in[5];
    float* out = (float*)d_out;

    char* ws = (char*)d_ws;
    int*    perm    = (int*)ws;                               // 16 KB
    int*    offsets = (int*)(ws + 16384);
    __bf16* xb      = (__bf16*)(ws + 32768);                  // 8 MB
    __bf16* H       = (__bf16*)(ws + 32768 + (8ull << 20));   // 32 MB
    __bf16* Wt1     = (__bf16*)(ws + 32768 + (40ull << 20));  // 64 MB (dead after gemm1)
    __bf16* Wt2     = (__bf16*)(ws + 32768 + (104ull << 20)); // 64 MB
    float*  partial = (float*)(ws + 32768 + (40ull << 20));   // 64 MB, overlays Wt1

    // Order so each weight matrix is consumed while still L3-resident.
    route_kernel<<<1, 256, 0, stream>>>(route, perm, offsets);
    convert_x_kernel<<<(BTOK * DIN / 4) / 256, 256, 0, stream>>>(x, xb);
    transpose_kernel<DIN, DHID><<<dim3(DHID / 128, DIN / 64, MEXP), 256, 0, stream>>>(W1, Wt1);
    gemm1_kernel<<<dim3(DHID / 128, 8, MEXP), 256, 0, stream>>>(xb, Wt1, b1, perm, offsets, H);
    transpose_kernel<DHID, DOUT><<<dim3(DOUT / 128, DHID / 64, MEXP), 256, 0, stream>>>(W2, Wt2);
    gemm2p_kernel<<<dim3(DOUT / 128, 8, MEXP * 4), 256, 0, stream>>>(H, Wt2, offsets, partial);
    reduce_kernel<<<BTOK, 256, 0, stream>>>(partial, perm, offsets, b2, out);
}

// Round 3
// 505.706 us; speedup vs baseline: 1.0136x; 1.0136x over previous
//
#include <hip/hip_runtime.h>
#include <math.h>

#define MEXP 8
#define BTOK 4096
#define DIN  1024
#define DHID 4096
#define DOUT 1024
#define BK   32

typedef __bf16 bf16x4 __attribute__((ext_vector_type(4)));
typedef __bf16 bf16x8 __attribute__((ext_vector_type(8)));
typedef float  f32x4  __attribute__((ext_vector_type(4)));

// async global->LDS, 16B per lane. LDS dest must be wave-uniform base + lane*16.
__device__ __forceinline__ void gld16(const void* g, void* l) {
    __builtin_amdgcn_global_load_lds(
        (const __attribute__((address_space(1))) unsigned int*)g,
        (__attribute__((address_space(3))) unsigned int*)l, 16, 0, 0);
}

__device__ __forceinline__ float gelu_tanh(float v) {
    float t = 1.5957691216057308f * v * (1.0f + 0.044715f * v * v);
    return v / (1.0f + __expf(-t));
}

// ---------------- routing ----------------
__global__ void route_kernel(const int* __restrict__ route, int* __restrict__ perm,
                             int* __restrict__ offsets) {
    __shared__ int cnt[MEXP];
    __shared__ int off[MEXP + 1];
    int t = threadIdx.x;
    if (t < MEXP) cnt[t] = 0;
    __syncthreads();
    for (int i = t; i < BTOK; i += blockDim.x) atomicAdd(&cnt[route[i]], 1);
    __syncthreads();
    if (t == 0) {
        int s = 0;
        for (int m = 0; m < MEXP; m++) { off[m] = s; s += cnt[m]; }
        off[MEXP] = s;
    }
    __syncthreads();
    if (t < MEXP + 1) offsets[t] = off[t];
    if (t < MEXP) cnt[t] = off[t];
    __syncthreads();
    for (int i = t; i < BTOK; i += blockDim.x) {
        int p = atomicAdd(&cnt[route[i]], 1);
        perm[p] = i;
    }
}

// ---------------- out[tok] = b2[expert] (base for gemm2 atomics) ----------------
__global__ __launch_bounds__(256)
void init_out_kernel(const int* __restrict__ perm, const int* __restrict__ offsets,
                     const float* __restrict__ b2, float* __restrict__ out) {
    int r = blockIdx.x;
    int e = 0;
#pragma unroll
    for (int q = 0; q < MEXP - 1; q++)
        if (r >= offsets[q + 1]) e = q + 1;
    int tok = perm[r];
    int c4 = threadIdx.x * 4;
    *(float4*)(out + (size_t)tok * DOUT + c4) = *(const float4*)(b2 + e * DOUT + c4);
}

// ---------------- x fp32 -> bf16 ----------------
__global__ __launch_bounds__(256) void convert_x_kernel(const float* __restrict__ x,
                                                        __bf16* __restrict__ xb) {
    int i = blockIdx.x * 256 + threadIdx.x;
    float4 v = *(const float4*)(x + (size_t)i * 4);
    bf16x4 p;
    p[0] = (__bf16)v.x; p[1] = (__bf16)v.y; p[2] = (__bf16)v.z; p[3] = (__bf16)v.w;
    *(bf16x4*)(xb + (size_t)i * 4) = p;
}

// ---------------- W [m][K][N] fp32 -> Wt [m][N][K] bf16 ----------------
template <int K, int N>
__global__ __launch_bounds__(256) void transpose_kernel(const float* __restrict__ W,
                                                        __bf16* __restrict__ Wt) {
    __shared__ float T[64][132];
    int m = blockIdx.z;
    int k0 = blockIdx.y * 64;
    int n0 = blockIdx.x * 128;
    const float* Wm = W + (size_t)m * K * N;
    __bf16* Wtm = Wt + (size_t)m * N * K;
    int t = threadIdx.x;
    int nc4 = (t & 31) * 4;
    int kr0 = t >> 5;
#pragma unroll
    for (int it = 0; it < 8; it++) {
        int kr = it * 8 + kr0;
        float4 v = *(const float4*)(Wm + (size_t)(k0 + kr) * N + n0 + nc4);
        *(float4*)&T[kr][nc4] = v;
    }
    __syncthreads();
#pragma unroll
    for (int it = 0; it < 4; it++) {
        int task = it * 256 + t;
        int nr = task >> 3;
        int gr = task & 7;
        bf16x8 v;
#pragma unroll
        for (int j = 0; j < 8; j++) {
            int j2 = (j + gr) & 7;
            v[j2] = (__bf16)T[gr * 8 + j2][nr];
        }
        *(bf16x8*)(Wtm + (size_t)(n0 + nr) * K + k0 + gr * 8) = v;
    }
}

// fragment reads + 16 MFMA on one 128x128 tile slice
#define GEMM_STAGE(Ap, Bp)                                                              \
    do {                                                                                \
        bf16x8 af[4], bfr[4];                                                           \
        _Pragma("unroll") for (int i = 0; i < 4; i++)                                   \
            af[i] = *(bf16x8*)&(Ap)[(wr + i * 16 + lm) * BK + quad * 8];                \
        _Pragma("unroll") for (int j = 0; j < 4; j++)                                   \
            bfr[j] = *(bf16x8*)&(Bp)[(wc + j * 16 + lm) * BK + quad * 8];               \
        _Pragma("unroll") for (int i = 0; i < 4; i++)                                   \
            _Pragma("unroll") for (int j = 0; j < 4; j++)                               \
                acc[i][j] = __builtin_amdgcn_mfma_f32_16x16x32_bf16(af[i], bfr[j],      \
                                                                   acc[i][j], 0, 0, 0);\
    } while (0)

#define PREFETCH(buf, kk)                                                               \
    do {                                                                                \
        gld16(gA[0] + (kk), lA[0] + (buf) * 8192);                                      \
        gld16(gA[1] + (kk), lA[1] + (buf) * 8192);                                      \
        gld16(gB[0] + (kk), lB[0] + (buf) * 8192);                                      \
        gld16(gB[1] + (kk), lB[1] + (buf) * 8192);                                      \
    } while (0)

// One pipeline stage: counted-vmcnt wait (loads for CUR buffer are the oldest 4 of 8
// in flight), raw barrier (no full drain!), prefetch 2 stages ahead, compute CUR.
// WAR-safe: buffer PRE=(s+2)%3 was last ds_read at stage s-1, before this barrier.
#define PSTAGE(CUR, PRE, KS, WN)                                                        \
    do {                                                                                \
        asm volatile("s_waitcnt vmcnt(" WN ")" ::: "memory");                           \
        __builtin_amdgcn_s_barrier();                                                   \
        __builtin_amdgcn_sched_barrier(0);                                              \
        if ((KS) < 32) PREFETCH(PRE, (KS) * BK);                                        \
        GEMM_STAGE(As + (CUR) * 4096, Bs + (CUR) * 4096);                               \
    } while (0)

#define PIPE_PROLOGUE()                                                                 \
    do { PREFETCH(0, 0); PREFETCH(1, BK); } while (0)

// 32 stages, buf = s%3, prefetch distance 2: stages 0..26 in triples, 27..31 explicit.
#define PIPE_LOOP()                                                                     \
    do {                                                                                \
        for (int it3 = 0; it3 < 27; it3 += 3) {                                         \
            PSTAGE(0, 2, it3 + 2, "4");                                                 \
            PSTAGE(1, 0, it3 + 3, "4");                                                 \
            PSTAGE(2, 1, it3 + 4, "4");                                                 \
        }                                                                               \
        PSTAGE(0, 2, 29, "4");                                                          \
        PSTAGE(1, 0, 30, "4");                                                          \
        PSTAGE(2, 1, 31, "4");                                                          \
        PSTAGE(0, 2, 32, "4");                                                          \
        PSTAGE(1, 0, 33, "0");                                                          \
    } while (0)

// ---------------- GEMM1: H[perm-space] = gelu(Xb[perm] @ W1t^T + b1) ----------------
// TM=128, TN=128, BK=32, 3-buffer prefetch-distance-2 with counted vmcnt.
__global__ __launch_bounds__(256)
void gemm1_kernel(const __bf16* __restrict__ xb, const __bf16* __restrict__ W1t,
                  const float* __restrict__ b1, const int* __restrict__ perm,
                  const int* __restrict__ offsets, __bf16* __restrict__ H) {
    int flat = blockIdx.x + 32 * (blockIdx.y + 8 * blockIdx.z);   // [0,2048)
    int logical = (flat & 7) * 256 + (flat >> 3);                 // bijective
    int m  = logical >> 8;          // expert -> XCD
    int bx = (logical >> 3) & 31;   // col tile
    int by = logical & 7;           // row tile

    int seg_start = offsets[m];
    int cnt = offsets[m + 1] - seg_start;
    int row0 = by * 128;
    if (row0 >= cnt) return;
    int col0 = bx * 128;

    __shared__ char smem[49152];           // As[3][4096] + Bs[3][4096] bf16
    __bf16* As = (__bf16*)smem;
    __bf16* Bs = (__bf16*)(smem + 24576);

    int tid = threadIdx.x;
    int wave = tid >> 6, lane = tid & 63;
    int wr = (wave >> 1) * 64, wc = (wave & 1) * 64;
    int lm = lane & 15, quad = lane >> 4;

    const __bf16* gA[2];
    char* lA[2];
    const __bf16* gB[2];
    char* lB[2];
    const __bf16* Wm = W1t + (size_t)m * DHID * DIN;
#pragma unroll
    for (int c = 0; c < 2; c++) {
        int rA = row0 + wave * 32 + c * 16 + (lane >> 2);
        int tok = perm[seg_start + (rA < cnt ? rA : cnt - 1)];
        gA[c] = xb + (size_t)tok * DIN + (lane & 3) * 8;
        lA[c] = smem + (wave * 32 + c * 16) * 64 + lane * 16;
        int nB = col0 + wave * 32 + c * 16 + (lane >> 2);
        gB[c] = Wm + (size_t)nB * DIN + (lane & 3) * 8;
        lB[c] = smem + 24576 + (wave * 32 + c * 16) * 64 + lane * 16;
    }

    f32x4 acc[4][4];
#pragma unroll
    for (int i = 0; i < 4; i++)
#pragma unroll
        for (int j = 0; j < 4; j++)
#pragma unroll
            for (int r = 0; r < 4; r++) acc[i][j][r] = 0.0f;

    PIPE_PROLOGUE();
    PIPE_LOOP();

    // ---- epilogue: bias+gelu -> LDS (swizzled) -> coalesced 16B row stores ----
    __syncthreads();                       // full drain before overlaying As/Bs
    __bf16* Ct = (__bf16*)smem;            // [128][128] bf16 = 32KB
#pragma unroll
    for (int j = 0; j < 4; j++) {
        int col = wc + j * 16 + lm;
        float bias = b1[m * DHID + col0 + col];
#pragma unroll
        for (int i = 0; i < 4; i++) {
#pragma unroll
            for (int r = 0; r < 4; r++) {
                int row = wr + i * 16 + quad * 4 + r;
                float v = acc[i][j][r] + bias;
                Ct[row * 128 + (col ^ ((row & 7) << 3))] = (__bf16)gelu_tanh(v);
            }
        }
    }
    __syncthreads();
#pragma unroll
    for (int it = 0; it < 8; it++) {
        int idx = it * 256 + tid;          // 2048 chunks of 16B
        int row = idx >> 4;
        int c = idx & 15;
        int grow = row0 + row;
        if (grow < cnt) {
            bf16x8 v = *(bf16x8*)&Ct[row * 128 + ((c * 8) ^ ((row & 7) << 3))];
            *(bf16x8*)(H + (size_t)(seg_start + grow) * DHID + col0 + c * 8) = v;
        }
    }
}

// ---------------- GEMM2 split-K=4, atomic accumulate into out ----------------
// TM=128, TN=128, BK=32, 3-buffer counted-vmcnt pipeline. grid (8, 8, MEXP*4).
__global__ __launch_bounds__(256)
void gemm2p_kernel(const __bf16* __restrict__ H, const __bf16* __restrict__ W2t,
                   const int* __restrict__ offsets, const int* __restrict__ perm,
                   float* __restrict__ out) {
    int flat = blockIdx.x + 8 * (blockIdx.y + 8 * blockIdx.z);    // [0,2048)
    int logical = (flat & 7) * 256 + (flat >> 3);
    int m  = logical >> 8;          // expert -> XCD
    int s  = (logical >> 6) & 3;    // K split
    int bx = (logical >> 3) & 7;
    int by = logical & 7;

    int seg_start = offsets[m];
    int cnt = offsets[m + 1] - seg_start;
    int row0 = by * 128;
    if (row0 >= cnt) return;
    int col0 = bx * 128;
    int kbase = s * (DHID / 4);

    __shared__ char smem[49152];
    __bf16* As = (__bf16*)smem;
    __bf16* Bs = (__bf16*)(smem + 24576);

    int tid = threadIdx.x;
    int wave = tid >> 6, lane = tid & 63;
    int wr = (wave >> 1) * 64, wc = (wave & 1) * 64;
    int lm = lane & 15, quad = lane >> 4;

    const __bf16* gA[2];
    char* lA[2];
    const __bf16* gB[2];
    char* lB[2];
    const __bf16* Wm = W2t + (size_t)m * DOUT * DHID;
#pragma unroll
    for (int c = 0; c < 2; c++) {
        int rA = row0 + wave * 32 + c * 16 + (lane >> 2);
        int hr = seg_start + (rA < cnt ? rA : cnt - 1);
        gA[c] = H + (size_t)hr * DHID + kbase + (lane & 3) * 8;
        lA[c] = smem + (wave * 32 + c * 16) * 64 + lane * 16;
        int nB = col0 + wave * 32 + c * 16 + (lane >> 2);
        gB[c] = Wm + (size_t)nB * DHID + kbase + (lane & 3) * 8;
        lB[c] = smem + 24576 + (wave * 32 + c * 16) * 64 + lane * 16;
    }

    f32x4 acc[4][4];
#pragma unroll
    for (int i = 0; i < 4; i++)
#pragma unroll
        for (int j = 0; j < 4; j++)
#pragma unroll
            for (int r = 0; r < 4; r++) acc[i][j][r] = 0.0f;

    PIPE_PROLOGUE();
    PIPE_LOOP();

    // ---- epilogue: atomic accumulate into out[tok] (b2 pre-written by init_out) ----
#pragma unroll
    for (int i = 0; i < 4; i++) {
#pragma unroll
        for (int r = 0; r < 4; r++) {
            int row = row0 + wr + i * 16 + quad * 4 + r;
            if (row < cnt) {
                int tok = perm[seg_start + row];
                float* orow = out + (size_t)tok * DOUT + col0 + wc + lm;
#pragma unroll
                for (int j = 0; j < 4; j++)
                    atomicAdd(orow + j * 16, acc[i][j][r]);
            }
        }
    }
}

extern "C" void kernel_launch(void* const* d_in, const int* in_sizes, int n_in,
                              void* d_out, int out_size, void* d_ws, size_t ws_size,
                              hipStream_t stream) {
    const float* x     = (const float*)d_in[0];
    const int*   route = (const int*)d_in[1];
    const float* W1    = (const float*)d_in[2];
    const float* b1    = (const float*)d_in[3];
    const float* W2    = (const float*)d_in[4];
    const float* b2    = (const float*)d_in[5];
    float* out = (float*)d_out;

    char* ws = (char*)d_ws;
    int*    perm    = (int*)ws;                               // 16 KB
    int*    offsets = (int*)(ws + 16384);
    __bf16* xb      = (__bf16*)(ws + 32768);                  // 8 MB
    __bf16* H       = (__bf16*)(ws + 32768 + (8ull << 20));   // 32 MB
    __bf16* Wt1     = (__bf16*)(ws + 32768 + (40ull << 20));  // 64 MB
    __bf16* Wt2     = (__bf16*)(ws + 32768 + (104ull << 20)); // 64 MB

    route_kernel<<<1, 256, 0, stream>>>(route, perm, offsets);
    init_out_kernel<<<BTOK, 256, 0, stream>>>(perm, offsets, b2, out);
    convert_x_kernel<<<(BTOK * DIN / 4) / 256, 256, 0, stream>>>(x, xb);
    transpose_kernel<DIN, DHID><<<dim3(DHID / 128, DIN / 64, MEXP), 256, 0, stream>>>(W1, Wt1);
    gemm1_kernel<<<dim3(DHID / 128, 8, MEXP), 256, 0, stream>>>(xb, Wt1, b1, perm, offsets, H);
    transpose_kernel<DHID, DOUT><<<dim3(DOUT / 128, DHID / 64, MEXP), 256, 0, stream>>>(W2, Wt2);
    gemm2p_kernel<<<dim3(DOUT / 128, 8, MEXP * 4), 256, 0, stream>>>(H, Wt2, offsets, perm, out);
}